// Round 5
// baseline (1940.719 us; speedup 1.0000x reference)
//
#include <hip/hip_runtime.h>

// ============================================================================
// Fully block-local attention-LSTM encoder. B=512, T-1=99, N=128, H=256.
//
// R10: R9 (1412 us) proved the block-local design: zero cross-block sync,
// weights streamed from L2. Remaining cost was VALU dot2 work (~6 us/step)
// serialized with the weight stream (~6.5 us/step). R10 moves gates+z1
// matvecs to MFMA (16x16x32 bf16, M=2 of 16 rows used -> still 12x fewer
// issue slots than dot2), with weights PRE-PACKED in B-fragment order by
// the pack kernel so the L2 stream is pure coalesced 16B/lane loads.
// A-fragments come from LDS (h|c or w); A rows >=2 are don't-care since
// C row r depends only on A row r. Phase order per step:
//   z1-MFMA -> barrier -> { h-gates MFMA stream ; E-phase tanh }  (one
//   barrier region -> 2 waves/SIMD co-schedule: tanh hides L2 latency)
//   -> softmax -> w-gates MFMA -> LSTM -> h,c to LDS.
// Step floor: 900 KB/CU / ~140 GB/s per-CU L2 port ~= 6.5 us.
//
// bf16 MFMA path is the R5-R8 compile- and accuracy-proven path (absmax
// 0.00049); z2/E stay f16 (R9-proven). 256 blocks x 512 threads, 1/CU.
// ============================================================================

typedef unsigned int  uint32;
typedef unsigned short u16;
typedef float  f4  __attribute__((ext_vector_type(4)));
typedef short  s8v __attribute__((ext_vector_type(8)));   // 8 bf16

#define TS 99
#define BB 512
#define NN 128
#define HH 256

__device__ __forceinline__ u16 f2bf(float f){
  union { float f; uint32 i; } v; v.f = f;
  uint32 r = v.i + 0x7FFFu + ((v.i >> 16) & 1u);   // RNE (finite values only)
  return (u16)(r >> 16);
}
__device__ __forceinline__ u16 f2h(float f){
  union { _Float16 h; u16 u; } v; v.h = (_Float16)f; return v.u;
}
__device__ __forceinline__ float h2ff(u16 u){
  union { u16 u2; _Float16 h; } v; v.u2 = u; return (float)v.h;
}
__device__ __forceinline__ float frcp(float x){ return __builtin_amdgcn_rcpf(x); }
__device__ __forceinline__ float ftanh(float x){
  float t = __expf(2.f * x);
  return 1.f - 2.f * frcp(t + 1.f);
}
__device__ __forceinline__ float fsig(float x){
  return frcp(1.f + __expf(-x));
}

struct KParams {
  const float *in, *W1, *b1, *W2, *b2, *W3, *Wih, *Whh, *bih, *bhh;
  float *out;          // [weighted B*99*128 | encoded B*99*256] f32
  const s8v *Wgpk;     // [12 kc][64 jt][64 lane][8] bf16 B-frags (Wih|Whh)
  const s8v *W1pk;     // [7 st][16 kc][64 lane][8]  bf16 B-frags (W1)
};

// ---- pack weights into MFMA B-fragment order (runs once) ----
// B-frag (proven R5 mapping): value(lane, jj) = W[col = tile*16 + (lane&15)]
//                                               [k   = kc*32 + (lane>>4)*8 + jj]
__global__ void pack_kernel(const float* W1, const float* Wih, const float* Whh,
                            u16* Wgpk, u16* W1pk)
{
  int idx = blockIdx.x * 256 + threadIdx.x;
  if (idx < 12 * 64 * 64 * 8) {                       // Wgpk: flat [kc][jt][lane][jj]
    int jj = idx & 7, lane = (idx >> 3) & 63, jt = (idx >> 9) & 63, kc = idx >> 15;
    int j  = jt * 16 + (lane & 15);
    int kk = kc * 32 + ((lane >> 4) * 8) + jj;
    float v = (kc < 4) ? Wih[(size_t)j * 128 + kk]
                       : Whh[(size_t)j * 256 + (kk - 128)];
    Wgpk[idx] = f2bf(v);
  } else {
    int v2 = idx - 12 * 64 * 64 * 8;
    if (v2 < 7 * 16 * 64 * 8) {                       // W1pk: flat [st][kc][lane][jj]
      int jj = v2 & 7, lane = (v2 >> 3) & 63, kc = (v2 >> 9) & 15, st = v2 >> 13;
      int col = st * 16 + (lane & 15);                // s index
      int kk  = kc * 32 + ((lane >> 4) * 8) + jj;     // k over [h(256)|c(256)]
      float v = (col < TS) ? W1[(size_t)col * 512 + kk] : 0.f;
      W1pk[v2] = f2bf(v);
    }
  }
}

__global__ __launch_bounds__(512, 1) void enc_kernel(KParams p)
{
  // stride 102 (odd dword count) -> bank spread for per-row u16 reads
  __shared__ __align__(16) u16   int_s[2][128][102];  // f16 in[b][n][t]
  __shared__ __align__(16) u16   z2s[2][128][102];    // f16 z2[b][n][s] (+b2)
  __shared__ __align__(16) u16   hcb[2][512];         // bf16 [h(256)|c(256)]
  __shared__ __align__(16) u16   wpb[2][128];         // bf16 w[n]
  __shared__ __align__(16) float z1s[2][112];
  __shared__ float epart[2][2][128];
  __shared__ float gl[2][1024];
  __shared__ float biasl[1024];
  __shared__ float w3s[128], b1s[128];

  const int tid = threadIdx.x;
  const int blk = blockIdx.x;
  const int b0  = blk * 2;               // this block's two batches

  float* outw = p.out;
  float* oute = p.out + (size_t)BB * TS * NN;

  const int wv  = tid >> 6, lane = tid & 63;
  const int m15 = lane & 15;
  const int q8  = (lane >> 4) * 8;
  const int r16 = lane >> 4;

  // ---------------- prologue ----------------
  for (int b = 0; b < 2; ++b) {          // stage inputs f16, column layout
    const float* src = p.in + (size_t)(b0 + b) * TS * NN;
    for (int idx = tid; idx < TS * NN; idx += 512) {
      int t = idx >> 7, n = idx & 127;
      int_s[b][n][t] = f2h(src[idx]);
    }
  }
  if (tid < 128) {
    w3s[tid] = (tid < TS) ? p.W3[tid] : 0.f;
    b1s[tid] = (tid < TS) ? p.b1[tid] : 0.f;
  }
  ((u16*)hcb)[tid]       = 0;            // h = c = 0 at t=0
  ((u16*)hcb)[tid + 512] = 0;
  biasl[tid]       = p.bih[tid]       + p.bhh[tid];
  biasl[tid + 512] = p.bih[tid + 512] + p.bhh[tid + 512];
  __syncthreads();
  {  // z2[b][n][s] = b2[s] + sum_t in[b][t][n] * W2[s][t]
    int n = tid & 127, b = (tid >> 7) & 1, hf = tid >> 8;
    int s0 = hf * 50, s1 = hf ? TS : 50;
    const u16* ir = int_s[b][n];
    for (int s = s0; s < s1; ++s) {
      float acc = p.b2[s];
      const float* w2r = p.W2 + s * TS;
      for (int tt = 0; tt + 1 < TS; tt += 2) {
        uint32 pr = *(const uint32*)&ir[tt];
        acc = fmaf(h2ff((u16)(pr & 0xFFFFu)),  w2r[tt],     acc);
        acc = fmaf(h2ff((u16)(pr >> 16)),      w2r[tt + 1], acc);
      }
      acc = fmaf(h2ff(ir[98]), w2r[98], acc);
      z2s[b][n][s] = f2h(acc);
    }
  }
  __syncthreads();

  float creg = 0.f;                      // c for (lb, lu), f32 forever
  const int lu = tid & 255, lb = tid >> 8;

  for (int t = 0; t < TS; ++t) {
    // ===== alpha: z1[b][s] = b1[s] + [h,c].W1[s][:]  (MFMA, waves 0-6) =====
    if (wv < 7) {
      f4 zacc = {0.f, 0.f, 0.f, 0.f};
      const s8v* wb = p.W1pk + (size_t)wv * 16 * 64 + lane;
      #pragma unroll
      for (int kc = 0; kc < 16; ++kc) {
        // A row r only feeds C row r: rows>=2 are don't-care -> no zeroing
        s8v av = *(const s8v*)&hcb[m15 & 1][kc * 32 + q8];
        zacc = __builtin_amdgcn_mfma_f32_16x16x32_bf16(av, wb[kc * 64], zacc,
                                                       0, 0, 0);
      }
      if (r16 == 0) {      // C: col=lane&15 -> s_local, rows 0,1 -> batch
        int s = wv * 16 + m15;
        z1s[0][s] = b1s[s] + zacc[0];
        z1s[1][s] = b1s[s] + zacc[1];
      }
    }
    __syncthreads();

    // ===== beta: h-gates MFMA stream (512KB) + E phase, one barrier region ==
    f4 acc0 = {0,0,0,0}, acc1 = {0,0,0,0}, acc2 = {0,0,0,0}, acc3 = {0,0,0,0};
    f4 acc4 = {0,0,0,0}, acc5 = {0,0,0,0}, acc6 = {0,0,0,0}, acc7 = {0,0,0,0};
    {
      const s8v* wg = p.Wgpk + lane + (size_t)(wv * 8) * 64;
      #pragma unroll
      for (int kc = 4; kc < 12; ++kc) {
        s8v av = *(const s8v*)&hcb[m15 & 1][(kc - 4) * 32 + q8];
        const s8v* wk = wg + (size_t)kc * 64 * 64;
        acc0 = __builtin_amdgcn_mfma_f32_16x16x32_bf16(av, wk[0 * 64], acc0, 0, 0, 0);
        acc1 = __builtin_amdgcn_mfma_f32_16x16x32_bf16(av, wk[1 * 64], acc1, 0, 0, 0);
        acc2 = __builtin_amdgcn_mfma_f32_16x16x32_bf16(av, wk[2 * 64], acc2, 0, 0, 0);
        acc3 = __builtin_amdgcn_mfma_f32_16x16x32_bf16(av, wk[3 * 64], acc3, 0, 0, 0);
        acc4 = __builtin_amdgcn_mfma_f32_16x16x32_bf16(av, wk[4 * 64], acc4, 0, 0, 0);
        acc5 = __builtin_amdgcn_mfma_f32_16x16x32_bf16(av, wk[5 * 64], acc5, 0, 0, 0);
        acc6 = __builtin_amdgcn_mfma_f32_16x16x32_bf16(av, wk[6 * 64], acc6, 0, 0, 0);
        acc7 = __builtin_amdgcn_mfma_f32_16x16x32_bf16(av, wk[7 * 64], acc7, 0, 0, 0);
      }
    }
    {  // E: e[b][n] = sum_s w3[s] * tanh(z1[b][s] + z2[b][n][s])
      int n = tid & 127, b = (tid >> 7) & 1, hf = tid >> 8;
      int s0 = hf * 50, s1 = hf ? TS : 50;
      const u16* zr = z2s[b][n];
      float acce = 0.f;
      for (int s = s0; s < s1; ++s)
        acce = fmaf(w3s[s], ftanh(z1s[b][s] + h2ff(zr[s])), acce);
      epart[b][hf][n] = acce;
    }
    __syncthreads();

    // ===== softmax + w = attn * x_t  (wave0 -> b0, wave1 -> b1) ============
    if (tid < 128) {
      int b = tid >> 6, ln = tid & 63;
      float v0 = epart[b][0][ln]      + epart[b][1][ln];
      float v1 = epart[b][0][ln + 64] + epart[b][1][ln + 64];
      float m = fmaxf(v0, v1);
      for (int off = 32; off; off >>= 1) m = fmaxf(m, __shfl_xor(m, off));
      float e0 = __expf(v0 - m), e1 = __expf(v1 - m);
      float sm = e0 + e1;
      for (int off = 32; off; off >>= 1) sm += __shfl_xor(sm, off);
      float r = frcp(sm);
      const float* xr = p.in + ((size_t)(b0 + b) * TS + t) * NN;
      float w0 = e0 * r * xr[ln];
      float w1 = e1 * r * xr[ln + 64];
      float* orow = outw + ((size_t)(b0 + b) * TS + t) * NN;
      orow[ln]      = w0;                // f32 output
      orow[ln + 64] = w1;
      wpb[b][ln]      = f2bf(w0);
      wpb[b][ln + 64] = f2bf(w1);
    }
    __syncthreads();

    // ===== gamma: w-gates MFMA (256KB) + write gl ==========================
    {
      const s8v* wg = p.Wgpk + lane + (size_t)(wv * 8) * 64;
      #pragma unroll
      for (int kc = 0; kc < 4; ++kc) {
        s8v av = *(const s8v*)&wpb[m15 & 1][kc * 32 + q8];
        const s8v* wk = wg + (size_t)kc * 64 * 64;
        acc0 = __builtin_amdgcn_mfma_f32_16x16x32_bf16(av, wk[0 * 64], acc0, 0, 0, 0);
        acc1 = __builtin_amdgcn_mfma_f32_16x16x32_bf16(av, wk[1 * 64], acc1, 0, 0, 0);
        acc2 = __builtin_amdgcn_mfma_f32_16x16x32_bf16(av, wk[2 * 64], acc2, 0, 0, 0);
        acc3 = __builtin_amdgcn_mfma_f32_16x16x32_bf16(av, wk[3 * 64], acc3, 0, 0, 0);
        acc4 = __builtin_amdgcn_mfma_f32_16x16x32_bf16(av, wk[4 * 64], acc4, 0, 0, 0);
        acc5 = __builtin_amdgcn_mfma_f32_16x16x32_bf16(av, wk[5 * 64], acc5, 0, 0, 0);
        acc6 = __builtin_amdgcn_mfma_f32_16x16x32_bf16(av, wk[6 * 64], acc6, 0, 0, 0);
        acc7 = __builtin_amdgcn_mfma_f32_16x16x32_bf16(av, wk[7 * 64], acc7, 0, 0, 0);
      }
      if (r16 == 0) {      // rows 0,1 = batches; col = j within tile
        int jb = wv * 8 * 16 + m15;
        gl[0][jb +   0] = acc0[0];  gl[1][jb +   0] = acc0[1];
        gl[0][jb +  16] = acc1[0];  gl[1][jb +  16] = acc1[1];
        gl[0][jb +  32] = acc2[0];  gl[1][jb +  32] = acc2[1];
        gl[0][jb +  48] = acc3[0];  gl[1][jb +  48] = acc3[1];
        gl[0][jb +  64] = acc4[0];  gl[1][jb +  64] = acc4[1];
        gl[0][jb +  80] = acc5[0];  gl[1][jb +  80] = acc5[1];
        gl[0][jb +  96] = acc6[0];  gl[1][jb +  96] = acc6[1];
        gl[0][jb + 112] = acc7[0];  gl[1][jb + 112] = acc7[1];
      }
    }
    __syncthreads();

    // ===== LSTM pointwise; thread = (lb, lu) fixed across steps ============
    {
      float iv = gl[lb][lu]       + biasl[lu];
      float fv = gl[lb][256 + lu] + biasl[256 + lu];
      float gv = gl[lb][512 + lu] + biasl[512 + lu];
      float ov = gl[lb][768 + lu] + biasl[768 + lu];
      float cn = fsig(fv) * creg + fsig(iv) * ftanh(gv);
      float hn = fsig(ov) * ftanh(cn);
      creg = cn;
      oute[((size_t)(b0 + lb) * TS + t) * HH + lu] = hn;   // f32 output
      hcb[lb][lu]       = f2bf(hn);
      hcb[lb][256 + lu] = f2bf(cn);
    }
    __syncthreads();
  }
}

extern "C" void kernel_launch(void* const* d_in, const int* in_sizes, int n_in,
                              void* d_out, int out_size, void* d_ws, size_t ws_size,
                              hipStream_t stream)
{
  KParams p;
  p.in  = (const float*)d_in[0];
  p.W1  = (const float*)d_in[1];
  p.b1  = (const float*)d_in[2];
  p.W2  = (const float*)d_in[3];
  p.b2  = (const float*)d_in[4];
  p.W3  = (const float*)d_in[5];
  // d_in[6] = b3: softmax shift-invariant, unused
  p.Wih = (const float*)d_in[7];
  p.Whh = (const float*)d_in[8];
  p.bih = (const float*)d_in[9];
  p.bhh = (const float*)d_in[10];
  p.out = (float*)d_out;

  char* ws = (char*)d_ws;
  const size_t wgpkBytes = 12ull * 64 * 64 * 8 * 2;   // 786,432
  const size_t w1pkBytes = 7ull * 16 * 64 * 8 * 2;    // 114,688
  const size_t needBytes = wgpkBytes + w1pkBytes;     // 901,120
  if (ws_size < needBytes) return;  // fail loudly (poisoned output)

  u16* Wgpk = (u16*)ws;
  u16* W1pk = (u16*)(ws + wgpkBytes);
  p.Wgpk = (const s8v*)Wgpk;
  p.W1pk = (const s8v*)W1pk;

  // pack weights into fragment order (fully covers both buffers; same-stream
  // ordering guarantees visibility to enc_kernel)
  const int packElems = 12 * 64 * 64 * 8 + 7 * 16 * 64 * 8;   // 450,560
  pack_kernel<<<dim3((packElems + 255) / 256), dim3(256), 0, stream>>>(
      p.W1, p.Wih, p.Whh, Wgpk, W1pk);

  enc_kernel<<<dim3(256), dim3(512), 0, stream>>>(p);
}